// Round 22
// baseline (526.657 us; speedup 1.0000x reference)
//
#include <hip/hip_runtime.h>
#include <hip/hip_bf16.h>
#include <math.h>

#define B_ 16
#define C_ 512
#define T_ 4096
#define I_ 1536

typedef short short8 __attribute__((ext_vector_type(8)));
typedef unsigned short ushort8 __attribute__((ext_vector_type(8)));
typedef unsigned short us4 __attribute__((ext_vector_type(4)));
typedef float f32x4 __attribute__((ext_vector_type(4)));
typedef int i32x4 __attribute__((ext_vector_type(4)));
typedef char char8v __attribute__((ext_vector_type(8)));

static __device__ __forceinline__ unsigned short f2bf(float f) {
  union { float f; unsigned int u; } v; v.f = f;
  unsigned int r = v.u + 0x7fffu + ((v.u >> 16) & 1u);
  return (unsigned short)(r >> 16);
}
static __device__ __forceinline__ float bf2f(unsigned short h) {
  union { unsigned int u; float f; } v; v.u = ((unsigned int)h) << 16;
  return v.f;
}

static __device__ __forceinline__ float fast_rcp(float x) {
  float r; asm("v_rcp_f32 %0, %1" : "=v"(r) : "v"(x)); return r;
}

// tanh-form GELU. |err vs erf| <= ~3e-3/elem, diluted by @W2.
static __device__ __forceinline__ float gelu_f(float v) {
  const float v2 = v * v;
  const float w = v * (0.7978845608f + 0.0356774081f * v2);
  const float a = fminf(w * 2.8853900818f, 126.0f);
  const float u = exp2f(a);
  return v * u * fast_rcp(u + 1.0f);
}

static __device__ __forceinline__ int q8i(float v, float inv) {
  int q = __float2int_rn(v * inv);
  q = q > 127 ? 127 : (q < -127 ? -127 : q);
  return q;
}
static __device__ __forceinline__ char q8(float v, float inv) {
  return (char)q8i(v, inv);
}

__device__ __forceinline__ void gload_lds16(const void* g, void* l) {
  __builtin_amdgcn_global_load_lds((const __attribute__((address_space(1))) void*)g,
                                   (__attribute__((address_space(3))) void*)l, 16, 0, 0);
}

#define H1S   (3.0f / 127.0f)
#define IH1S  (127.0f / 3.0f)

// kappa-permutation within each 128-col block
static __device__ __forceinline__ int kappa_to_c(int k128) {
  const int wcbit = k128 >> 6, lrow = (k128 & 63) >> 2, n = k128 & 3;
  return wcbit * 64 + n * 16 + lrow;
}
static __device__ __forceinline__ int c_to_kappa(int c128) {
  return (c128 >> 6) * 64 + (c128 & 15) * 4 + ((c128 & 63) >> 4);
}

// 4-chunk staging swizzle (64B rows)
static __device__ __forceinline__ int swz_kc(int q, int row) {
  return (q & 3) ^ ((row >> 1) & 3);
}
static __device__ __forceinline__ int swz_rd(int row, int lg) {
  return row * 4 + (lg ^ ((row >> 1) & 3));
}
// 8-chunk staging swizzle (128B rows, bf16 BK=64)
static __device__ __forceinline__ int swz8_kc(int q, int row) {
  return (q & 7) ^ ((row >> 1) & 7);
}
static __device__ __forceinline__ int swz8_rd(int row, int chunk) {
  return row * 8 + (chunk ^ ((row >> 1) & 7));
}

// ---------------- precompute stage A: kv + weight scales ----------------

__global__ __launch_bounds__(256) void pre_a(const float* __restrict__ aux,
                                             const float* __restrict__ Wkv,
                                             const float* __restrict__ bkv,
                                             const float* __restrict__ W1,
                                             const float* __restrict__ W2,
                                             float* __restrict__ kv,
                                             float* __restrict__ w1s,
                                             float* __restrict__ w2s) {
  __shared__ unsigned int red;
  const int bid = blockIdx.x;
  const int tid = threadIdx.x;
  if (bid < 256) {
    const int g = bid * 256 + tid;              // 65536 = 64 * 1024
    const int j = g >> 10, cc = g & 1023;
    float s = bkv[cc];
    for (int i = 0; i < C_; ++i) s += aux[j * C_ + i] * Wkv[i * (2 * C_) + cc];
    kv[g] = s;
    return;
  }
  const bool isW1 = bid < 256 + 1536;
  const int n = isW1 ? (bid - 256) : (bid - 256 - 1536);
  const int ROWS = isW1 ? 512 : 1536;
  const int NC   = isW1 ? 1536 : 512;
  const float* W = isW1 ? W1 : W2;
  if (tid == 0) red = 0;
  __syncthreads();
  float amax = 0.f;
  for (int k = tid; k < ROWS; k += 256)
    amax = fmaxf(amax, fabsf(W[(size_t)k * NC + n]));
#pragma unroll
  for (int off = 1; off < 64; off <<= 1)
    amax = fmaxf(amax, __shfl_xor(amax, off));
  if ((tid & 63) == 0) atomicMax(&red, __float_as_uint(amax));
  __syncthreads();
  if (tid == 0) (isW1 ? w1s : w2s)[n] = fmaxf(__uint_as_float(red), 1e-20f) / 127.0f;
}

// ---------------- precompute stage B: MT, cb, VoT(kappa) ----------------

__global__ __launch_bounds__(256) void pre_b(const float* __restrict__ Wq,
                                             const float* __restrict__ bq,
                                             const float* __restrict__ Wo,
                                             const float* __restrict__ kv,
                                             unsigned short* __restrict__ MT,
                                             float* __restrict__ cbias,
                                             unsigned short* __restrict__ VoT) {
  const int bid = blockIdx.x;
  const int tid = threadIdx.x;
  if (bid < 512) {
    const int col = bid;
    const int h = col >> 6, j = col & 63;
    const float* kvp = kv + j * 1024 + h * 64;
    for (int c = tid; c < C_; c += 256) {
      float s = 0.f;
      for (int d = 0; d < 64; ++d) s += Wq[(size_t)c * C_ + h * 64 + d] * kvp[d];
      MT[(size_t)col * C_ + c] = f2bf(0.125f * s);
    }
    if (tid == 0) {
      float s = 0.f;
      for (int d = 0; d < 64; ++d) s += bq[h * 64 + d] * kvp[d];
      cbias[col] = 0.125f * s;
    }
  } else {
    const int cp = bid - 512;
    for (int k = tid; k < 512; k += 256) {
      const int c = (k >> 7) * 128 + kappa_to_c(k & 127);   // true attention col
      const int h = c >> 6, j = c & 63;
      float s = 0.f;
      for (int d = 0; d < 64; ++d)
        s += kv[j * 1024 + 512 + h * 64 + d] * Wo[(size_t)(h * 64 + d) * C_ + cp];
      VoT[(size_t)cp * 512 + k] = f2bf(s);
    }
  }
}

// ---------------- precompute stage W: coalesced transpose-quantize of W1/W2 ----------------

__global__ __launch_bounds__(256) void pre_w(const float* __restrict__ W1,
                                             const float* __restrict__ W2,
                                             const float* __restrict__ w1s,
                                             const float* __restrict__ w2s,
                                             char* __restrict__ W1Q,
                                             char* __restrict__ W2Q) {
  __shared__ char tile[64 * 132];
  __shared__ float invs[64];
  const int bid = blockIdx.x, tid = threadIdx.x;
  const bool isW1 = bid < 96;
  int n0, k0, NC;
  if (isW1) { n0 = (bid >> 2) * 64; k0 = (bid & 3) * 128; NC = 1536; }
  else      { const int t = bid - 96; n0 = (t / 12) * 64; k0 = (t % 12) * 128; NC = 512; }
  const float* W = isW1 ? W1 : W2;
  if (tid < 64) invs[tid] = 1.0f / (isW1 ? w1s[n0 + tid] : w2s[n0 + tid]);
  __syncthreads();
  const int n = tid & 63;
  const float inv = invs[n];
#pragma unroll
  for (int s = 0; s < 32; ++s) {
    const int f = s * 256 + tid;
    const int r = f >> 6;                       // 0..127
    const int pr = isW1 ? r : c_to_kappa(r);    // kappa k-permutation for W2
    tile[n * 132 + pr] = q8(W[(size_t)(k0 + r) * NC + n0 + n], inv);
  }
  __syncthreads();
#pragma unroll
  for (int s = 0; s < 2; ++s) {
    const int idx = s * 256 + tid;              // 512 = 64n x 8kc
    const int nn = idx >> 3, kc = idx & 7;
    i32x4 pk;
#pragma unroll
    for (int j = 0; j < 4; ++j)
      pk[j] = *(const int*)&tile[nn * 132 + kc * 16 + j * 4];
    if (isW1) *(i32x4*)&W1Q[(size_t)(n0 + nn) * 512 + k0 + kc * 16] = pk;
    else      *(i32x4*)&W2Q[(size_t)(n0 + nn) * 1536 + k0 + kc * 16] = pk;
  }
}

// ---------------- x (B,C,T) -> xt bf16 (B*T, C), vectorized stores ----------------

__global__ __launch_bounds__(256) void xt_kernel(const float* __restrict__ x,
                                                 unsigned short* __restrict__ xt) {
  __shared__ float ld[64][65];
  const int tid = threadIdx.x;
  const int t0 = blockIdx.x * 64, c0 = blockIdx.y * 64, b = blockIdx.z;
  for (int idx = tid; idx < 4096; idx += 256) {
    const int r = idx >> 6, cc = idx & 63;
    ld[r][cc] = x[((size_t)(b * C_ + c0 + r)) * T_ + t0 + cc];
  }
  __syncthreads();
#pragma unroll
  for (int s = 0; s < 2; ++s) {
    const int idx = s * 256 + tid;      // 512 = 64 t-rows x 8 col-chunks
    const int tr = idx >> 3, cl8 = (idx & 7) * 8;
    ushort8 o;
#pragma unroll
    for (int qv = 0; qv < 8; ++qv) o[qv] = f2bf(ld[cl8 + qv][tr]);
    *(ushort8*)&xt[((size_t)(b * T_ + t0 + tr)) * C_ + c0 + cl8] = o;
  }
}

// ---------------- GEMM A (m97, BK=64, 8-chunk coalesced swizzled staging) ----------------
template<int N, int K, int NCOL, int EPI>
__global__ __launch_bounds__(256) void gemm_mfma(const unsigned short* __restrict__ A,
                                                 const unsigned short* __restrict__ Bt,
                                                 const float* __restrict__ bias,
                                                 unsigned short* __restrict__ outU,
                                                 const unsigned short* __restrict__ resU,
                                                 float* __restrict__ outF) {
  __shared__ __align__(16) unsigned short shm[EPI == 4 ? 128 * 132 : 128 * 128];
  unsigned short* lA = shm;              // 128 rows x 64 k (8 chunks/row)
  unsigned short* lB = shm + 128 * 64;
  unsigned short* bounce = shm;          // EPI4 only, after K-loop (lA/lB dead)
  const int q = gridDim.x >> 3;
  const int wgid = (blockIdx.x & 7) * q + (blockIdx.x >> 3);
  const int row0 = (wgid / NCOL) * 128;
  const int col0 = (wgid % NCOL) * 128;
  const int tid = threadIdx.x;
  const int w = tid >> 6, lane = tid & 63;
  const int wr = (w >> 1) * 64, wc = (w & 1) * 64;

  const f32x4 zero4 = {0.f, 0.f, 0.f, 0.f};
  f32x4 acc[4][4];
#pragma unroll
  for (int m = 0; m < 4; ++m)
#pragma unroll
    for (int n = 0; n < 4; ++n) acc[m][n] = zero4;

  const int lrow = lane & 15, lg = lane >> 4;

  // hoisted per-thread staging source pointers (one per s-slice)
  const unsigned short* aP[4];
  const unsigned short* bP[4];
#pragma unroll
  for (int s = 0; s < 4; ++s) {
    const int qq = s * 256 + tid;
    const int r = qq >> 3;
    const int kc = swz8_kc(qq, r);
    aP[s] = A + (size_t)(row0 + r) * K + kc * 8;
    bP[s] = Bt + (size_t)(col0 + r) * K + kc * 8;
  }

  for (int k0 = 0; k0 < K; k0 += 64) {
#pragma unroll
    for (int s = 0; s < 4; ++s) {
      const int qq = s * 256 + tid;
      gload_lds16(aP[s] + k0, (char*)lA + qq * 16);
      gload_lds16(bP[s] + k0, (char*)lB + qq * 16);
    }
    __syncthreads();
    short8 av[2][4], bv[2][4];
#pragma unroll
    for (int ks = 0; ks < 2; ++ks) {
      const int ch = ks * 4 + lg;
#pragma unroll
      for (int m = 0; m < 4; ++m) {
        const int ar = wr + m * 16 + lrow;
        av[ks][m] = *(const short8*)&lA[swz8_rd(ar, ch) * 8];
        const int br = wc + m * 16 + lrow;
        bv[ks][m] = *(const short8*)&lB[swz8_rd(br, ch) * 8];
      }
    }
#pragma unroll
    for (int ks = 0; ks < 2; ++ks)
#pragma unroll
      for (int m = 0; m < 4; ++m)
#pragma unroll
        for (int n = 0; n < 4; ++n)
          acc[m][n] = __builtin_amdgcn_mfma_f32_16x16x32_bf16(av[ks][m], bv[ks][n],
                                                              acc[m][n], 0, 0, 0);
    __syncthreads();
  }

  if (EPI == 1) {
    float cbv[4];
#pragma unroll
    for (int n = 0; n < 4; ++n) cbv[n] = bias[col0 + wc + n * 16 + lrow];
    const int kbase = col0 + wc + lrow * 4;
#pragma unroll
    for (int m = 0; m < 4; ++m) {
#pragma unroll
      for (int i = 0; i < 4; ++i) {
        float e0 = acc[m][0][i] + cbv[0];
        float e1 = acc[m][1][i] + cbv[1];
        float e2 = acc[m][2][i] + cbv[2];
        float e3 = acc[m][3][i] + cbv[3];
        float mx = fmaxf(fmaxf(e0, e1), fmaxf(e2, e3));
        mx = fmaxf(mx, __shfl_xor(mx, 1));
        mx = fmaxf(mx, __shfl_xor(mx, 2));
        mx = fmaxf(mx, __shfl_xor(mx, 4));
        mx = fmaxf(mx, __shfl_xor(mx, 8));
        e0 = __expf(e0 - mx); e1 = __expf(e1 - mx);
        e2 = __expf(e2 - mx); e3 = __expf(e3 - mx);
        float s = e0 + e1 + e2 + e3;
        s += __shfl_xor(s, 1);
        s += __shfl_xor(s, 2);
        s += __shfl_xor(s, 4);
        s += __shfl_xor(s, 8);
        const float inv = 1.0f / s;
        us4 pk;
        pk[0] = f2bf(e0 * inv); pk[1] = f2bf(e1 * inv);
        pk[2] = f2bf(e2 * inv); pk[3] = f2bf(e3 * inv);
        *(us4*)&outU[(size_t)(row0 + wr + m * 16 + lg * 4 + i) * N + kbase] = pk;
      }
    }
    return;
  }

  // EPI == 4 : residual epilogue with LDS transpose bounce
#pragma unroll
  for (int m = 0; m < 4; ++m) {
    const int r0 = row0 + wr + m * 16 + (lg << 2);
    const int tl = wr + m * 16 + (lg << 2);
#pragma unroll
    for (int n = 0; n < 4; ++n) {
      const int cl = wc + n * 16 + lrow;
      const int c = col0 + cl;
      const float bb = bias[c];
      us4 pk;
#pragma unroll
      for (int i = 0; i < 4; ++i)
        pk[i] = f2bf(bf2f(resU[(size_t)(r0 + i) * 512 + c]) + acc[m][n][i] + bb);
      *(us4*)&bounce[cl * 132 + tl] = pk;
    }
  }
  __syncthreads();
  const int bidx = row0 >> 12;
  const int t0 = row0 & 4095;
#pragma unroll
  for (int j = 0; j < 8; ++j) {
    const int cl = j * 16 + w * 4 + (lane >> 4);
    const int t = (lane & 15) * 8;
    const ushort8 v = *(const ushort8*)&bounce[cl * 132 + t];
    *(ushort8*)&outU[((size_t)(bidx * C_ + col0 + cl)) * T_ + t0 + t] = v;
  }
}

// ---------------- GEMM B: int8, 4 waves, 128x128 tile, BK=64, 3-buf, 3 blocks/CU ----------
// Wave grid 2x2 (wm=w>>1, wn=w&1); per-wave 64x64 = acc[4][4]. LDS 48KB -> 3 blocks/CU.
// Staging coalesced+swizzled (R18 mechanism). EPI 3: kappa-packed char4 stores.
// EPI 5: 2-pass (64c each) LDS-bounce -> coalesced f32x4 stores.
template<int N, int K, int NCOL, int EPI>
__global__ __launch_bounds__(256, 3) void gemm8w(const char* __restrict__ A,
                                                 const char* __restrict__ Bt,
                                                 const float* __restrict__ rowS,
                                                 const float* __restrict__ colS,
                                                 const float* __restrict__ bias,
                                                 char* __restrict__ outQ,
                                                 const unsigned short* __restrict__ resU,
                                                 float* __restrict__ outF) {
  __shared__ __align__(16) char lds[49152];     // A bufs: b*8192; B bufs: 24576+b*8192
  const int tid = threadIdx.x;
  const int w = tid >> 6, lane = tid & 63;
  const int wm = w >> 1, wn = w & 1;            // 2x2 wave grid
  const int lrow = lane & 15, lg = lane >> 4;
  const int q8g = gridDim.x >> 3;
  const int wgid = (blockIdx.x & 7) * q8g + (blockIdx.x >> 3);
  const int row0 = (wgid / NCOL) * 128;
  const int col0 = (wgid % NCOL) * 128;

  // hoisted per-thread staging source pointers (2 chunks/thread per operand)
  const char* aP[2];
  const char* bP[2];
#pragma unroll
  for (int s = 0; s < 2; ++s) {
    const int q = s * 256 + tid;
    const int r = q >> 2, kc = swz_kc(q, r);
    aP[s] = A + (size_t)(row0 + r) * K + kc * 16;
    bP[s] = Bt + (size_t)(col0 + r) * K + kc * 16;
  }
  auto stage = [&](int kt, int b) {
#pragma unroll
    for (int s = 0; s < 2; ++s) {
      const int q = s * 256 + tid;
      gload_lds16(aP[s] + kt * 64, lds + b * 8192 + q * 16);
      gload_lds16(bP[s] + kt * 64, lds + 24576 + b * 8192 + q * 16);
    }
  };

  const i32x4 zero4 = {0, 0, 0, 0};
  i32x4 acc[4][4];
#pragma unroll
  for (int m = 0; m < 4; ++m)
#pragma unroll
    for (int n = 0; n < 4; ++n) acc[m][n] = zero4;

  const int KT = K / 64;     // G3: 8, G4: 24

  stage(0, 0);
  stage(1, 1);
  asm volatile("s_waitcnt vmcnt(4)" ::: "memory");
  __builtin_amdgcn_s_barrier();

  int cur = 0;
  for (int t = 0; t < KT; ++t) {
    if (t + 2 < KT) {
      const int nb = (cur + 2 >= 3) ? cur - 1 : cur + 2;
      stage(t + 2, nb);
    }
    const char* ab = lds + cur * 8192;
    const char* bb = lds + 24576 + cur * 8192;
    i32x4 av[4], bv[4];
#pragma unroll
    for (int mf = 0; mf < 4; ++mf) {
      const int ar = wm * 64 + mf * 16 + lrow;
      av[mf] = *(const i32x4*)(ab + (size_t)swz_rd(ar, lg) * 16);
    }
#pragma unroll
    for (int nf = 0; nf < 4; ++nf) {
      const int br = wn * 64 + nf * 16 + lrow;
      bv[nf] = *(const i32x4*)(bb + (size_t)swz_rd(br, lg) * 16);
    }
    __builtin_amdgcn_s_setprio(1);
#pragma unroll
    for (int mf = 0; mf < 4; ++mf)
#pragma unroll
      for (int nf = 0; nf < 4; ++nf)
        acc[mf][nf] = __builtin_amdgcn_mfma_i32_16x16x64_i8(av[mf], bv[nf],
                                                            acc[mf][nf], 0, 0, 0);
    __builtin_amdgcn_s_setprio(0);
    if (t + 2 < KT) { asm volatile("s_waitcnt vmcnt(4)" ::: "memory"); }
    else            { asm volatile("s_waitcnt vmcnt(0)" ::: "memory"); }
    __builtin_amdgcn_s_barrier();
    cur = (cur == 2) ? 0 : cur + 1;
  }

  if (EPI == 3) {
    // kappa within this 128-block: wcbit = wn; kbase = col0 + wn*64 + lrow*4
    const int kbase = col0 + wn * 64 + lrow * 4;
#pragma unroll
    for (int mf = 0; mf < 4; ++mf) {
      const int r0 = row0 + wm * 64 + mf * 16 + lg * 4;
      float rs4[4];
#pragma unroll
      for (int i = 0; i < 4; ++i) rs4[i] = rowS[r0 + i];
      float dsv[4], bbv[4];
#pragma unroll
      for (int nf = 0; nf < 4; ++nf) {
        const int c = col0 + wn * 64 + nf * 16 + lrow;
        dsv[nf] = colS[c];
        bbv[nf] = bias[c];
      }
#pragma unroll
      for (int i = 0; i < 4; ++i) {
        unsigned int pk = 0;
#pragma unroll
        for (int nf = 0; nf < 4; ++nf) {
          const float v = fmaf((float)acc[mf][nf][i], rs4[i] * dsv[nf], bbv[nf]);
          const float g = gelu_f(v);
          const unsigned int b = (unsigned int)(unsigned char)(char)q8i(g, IH1S);
          pk |= b << (8 * nf);
        }
        *(unsigned int*)&outQ[(size_t)(r0 + i) * N + kbase] = pk;
      }
    }
    return;
  }

  // EPI == 5 : 2-pass LDS bounce (64c x 128t f32, stride 132) -> coalesced stores
  float* fb = (float*)lds;
  const int bidx = row0 >> 12;
  const int t0 = row0 & 4095;
#pragma unroll
  for (int p = 0; p < 2; ++p) {
    if (wn == p) {
#pragma unroll
      for (int mf = 0; mf < 4; ++mf) {
        const int tl = wm * 64 + mf * 16 + lg * 4;
#pragma unroll
        for (int nf = 0; nf < 4; ++nf) {
          const int cl = nf * 16 + lrow;        // 0..63
          const int c = col0 + p * 64 + cl;
          const float ds = H1S * colS[c];
          const float bb = bias[c];
          f32x4 v;
#pragma unroll
          for (int i = 0; i < 4; ++i) v[i] = fmaf((float)acc[mf][nf][i], ds, bb);
          *(f32x4*)&fb[cl * 132 + tl] = v;
        }
      }
    }
    __syncthreads();
#pragma unroll
    for (int j = 0; j < 8; ++j) {
      const int cl = j * 8 + w * 2 + (lane >> 5);   // 0..63
      const int t = (lane & 31) * 4;
      const f32x4 v = *(const f32x4*)&fb[cl * 132 + t];
      const size_t addr = ((size_t)(bidx * C_ + col0 + p * 64 + cl)) * T_ + t0 + t;
      const us4 rv = *(const us4*)&resU[addr];
      f32x4 o;
#pragma unroll
      for (int i = 0; i < 4; ++i) o[i] = v[i] + bf2f(rv[i]);
      *(f32x4*)&outF[addr] = o;
    }
    __syncthreads();
  }
}

// ---------------- fused conv1d(k=7,p=3) + AdaLayerNorm -> int8 yln + per-token scale --------

__global__ __launch_bounds__(256) void convq_kernel(
    const unsigned short* __restrict__ rs,
    const float* __restrict__ dww,
    const float* __restrict__ dwb,
    const int* __restrict__ ids,
    const float* __restrict__ sce,
    const float* __restrict__ she,
    char* __restrict__ ylnq,
    float* __restrict__ yscale) {
  __shared__ unsigned short rbuf[512 * 28];   // [c][16t window + pad]
  __shared__ float cbuf[8 * 520];
  const int tid = threadIdx.x;
  const int t0 = blockIdx.x * 8;
  const int b = blockIdx.y;
  const int w0 = t0 - 4;                      // window [w0, w0+16)
#pragma unroll
  for (int s = 0; s < 8; ++s) {
    const int f = s * 256 + tid;
    const int c = f >> 2, j = f & 3;
    const int t = w0 + j * 4;
    us4 v = {0, 0, 0, 0};
    if (t >= 0 && t + 3 < T_) {
      v = *(const us4*)&rs[((size_t)(b * C_ + c)) * T_ + t];
    } else {
#pragma unroll
      for (int e = 0; e < 4; ++e)
        if (t + e >= 0 && t + e < T_) v[e] = rs[((size_t)(b * C_ + c)) * T_ + t + e];
    }
    *(us4*)&rbuf[c * 28 + j * 4] = v;
  }
  __syncthreads();
#pragma unroll
  for (int cc = 0; cc < 2; ++cc) {
    const int c = cc * 256 + tid;
    float f[15];
#pragma unroll
    for (int i = 0; i < 15; ++i) f[i] = bf2f(rbuf[c * 28 + i]);
    float wk[7];
#pragma unroll
    for (int k = 0; k < 7; ++k) wk[k] = dww[c * 7 + k];
    const float bb = dwb[c];
#pragma unroll
    for (int tt = 0; tt < 8; ++tt) {
      float s = bb;
#pragma unroll
      for (int k = 0; k < 7; ++k) s += f[tt + 1 + k] * wk[k];
      cbuf[tt * 520 + c] = s;
    }
  }
  __syncthreads();
  const int lane = tid & 63, w = tid >> 6;
  const int id = ids[b];
#pragma unroll
  for (int tt = 0; tt < 2; ++tt) {
    const int t = w * 2 + tt;
    const f32x4 v0 = *(const f32x4*)&cbuf[t * 520 + lane * 8];
    const f32x4 v1 = *(const f32x4*)&cbuf[t * 520 + lane * 8 + 4];
    float s = 0.f, sq = 0.f;
#pragma unroll
    for (int i = 0; i < 4; ++i) { s += v0[i]; sq += v0[i] * v0[i]; }
#pragma unroll
    for (int i = 0; i < 4; ++i) { s += v1[i]; sq += v1[i] * v1[i]; }
#pragma unroll
    for (int off = 1; off < 64; off <<= 1) {
      s += __shfl_xor(s, off);
      sq += __shfl_xor(sq, off);
    }
    const float mean = s * (1.0f / 512.0f);
    const float var = sq * (1.0f / 512.0f) - mean * mean;
    const float rstd = rsqrtf(var + 1e-6f);
    const f32x4 sc0 = *(const f32x4*)&sce[id * C_ + lane * 8];
    const f32x4 sc1 = *(const f32x4*)&sce[id * C_ + lane * 8 + 4];
    const f32x4 sh0 = *(const f32x4*)&she[id * C_ + lane * 8];
    const f32x4 sh1 = *(const f32x4*)&she[id * C_ + lane * 8 + 4];
    float y[8];
    float amax = 0.f;
#pragma unroll
    for (int i = 0; i < 4; ++i) {
      y[i]     = (v0[i] - mean) * rstd * sc0[i] + sh0[i];
      y[4 + i] = (v1[i] - mean) * rstd * sc1[i] + sh1[i];
    }
#pragma unroll
    for (int i = 0; i < 8; ++i) amax = fmaxf(amax, fabsf(y[i]));
#pragma unroll
    for (int off = 1; off < 64; off <<= 1) amax = fmaxf(amax, __shfl_xor(amax, off));
    amax = fmaxf(amax, 1e-20f);
    const float inv = 127.0f / amax;
    const int tg = b * T_ + t0 + t;
    char8v o;
#pragma unroll
    for (int i = 0; i < 8; ++i) o[i] = q8(y[i], inv);
    *(char8v*)&ylnq[(size_t)tg * C_ + lane * 8] = o;
    if (lane == 0) yscale[tg] = amax * (1.0f / 127.0f);
  }
}

// ---------------- launch ----------------

extern "C" void kernel_launch(void* const* d_in, const int* in_sizes, int n_in,
                              void* d_out, int out_size, void* d_ws, size_t ws_size,
                              hipStream_t stream) {
  const float* x   = (const float*)d_in[0];
  const int*   ids = (const int*)d_in[1];
  const float* Wq  = (const float*)d_in[2];
  const float* bq  = (const float*)d_in[3];
  const float* Wkv = (const float*)d_in[4];
  const float* bkv = (const float*)d_in[5];
  const float* Wo  = (const float*)d_in[6];
  const float* bo  = (const float*)d_in[7];
  const float* dww = (const float*)d_in[8];
  const float* dwb = (const float*)d_in[9];
  const float* sce = (const float*)d_in[10];
  const float* she = (const float*)d_in[11];
  const float* W1  = (const float*)d_in[12];
  const float* b1  = (const float*)d_in[13];
  const float* W2  = (const float*)d_in[14];
  const float* b2  = (const float*)d_in[15];
  const float* aux = (const float*)d_in[16];
  float* out = (float*)d_out;

  char* ws = (char*)d_ws;
  unsigned short* xt   = (unsigned short*)(ws + 0);              // 64 MB
  unsigned short* P    = (unsigned short*)(ws + (64u  << 20));   // 64 MB
  char*           ylnq = (char*)(ws + (64u << 20));              // 32 MB (overlays P; P dead)
  float*          ysc  = (float*)(ws + (100u << 20));            // 256 KB
  unsigned short* rs   = (unsigned short*)(ws + (128u << 20));   // 64 MB (bf16)
  char*           H1Q  = (char*)(ws + (192u << 20));             // 96 MB (i8)
  char* sm = ws + (384u << 20);
  float*          kv   = (float*)(sm);                           // 256 KB
  float*          cb   = (float*)(sm + 262144);                  // 2 KB
  unsigned short* MT   = (unsigned short*)(sm + 264192);         // 512 KB
  unsigned short* VoT  = (unsigned short*)(sm + 788480);         // 512 KB
  char*           W1Q  = (char*)(sm + 1312768);                  // 768 KB
  char*           W2Q  = (char*)(sm + 2099200);                  // 768 KB
  float*          w1s  = (float*)(sm + 2885632);                 // 6 KB
  float*          w2s  = (float*)(sm + 2891776);                 // 2 KB

  pre_a<<<dim3(2304), dim3(256), 0, stream>>>(aux, Wkv, bkv, W1, W2, kv, w1s, w2s);
  pre_b<<<dim3(1024), dim3(256), 0, stream>>>(Wq, bq, Wo, kv, MT, cb, VoT);
  pre_w<<<dim3(192),  dim3(256), 0, stream>>>(W1, W2, w1s, w2s, W1Q, W2Q);
  xt_kernel<<<dim3(64, 8, 16), dim3(256), 0, stream>>>(x, xt);

  // attention as two BK=64 m97-structure GEMMs with packed/bounced epilogues
  gemm_mfma<512, 512, 4, 1><<<dim3(2048), dim3(256), 0, stream>>>(
      xt, MT, cb, P, nullptr, nullptr);
  gemm_mfma<512, 512, 4, 4><<<dim3(2048), dim3(256), 0, stream>>>(
      P, VoT, bo, rs, xt, nullptr);
  convq_kernel<<<dim3(512, 16), dim3(256), 0, stream>>>(rs, dww, dwb, ids, sce, she,
                                                        ylnq, ysc);
  // MLP as two int8 4-wave 128x128 GEMMs (3 blocks/CU)
  gemm8w<1536, 512, 12, 3><<<dim3(6144), dim3(256), 0, stream>>>(
      ylnq, W1Q, ysc, w1s, b1, H1Q, nullptr, nullptr);
  gemm8w<512, 1536, 4, 5><<<dim3(2048), dim3(256), 0, stream>>>(
      H1Q, W2Q, nullptr, w2s, b2, nullptr, rs, out);
}

// Round 23
// 521.902 us; speedup vs baseline: 1.0091x; 1.0091x over previous
//
#include <hip/hip_runtime.h>
#include <hip/hip_bf16.h>
#include <math.h>

#define B_ 16
#define C_ 512
#define T_ 4096
#define I_ 1536

typedef short short8 __attribute__((ext_vector_type(8)));
typedef unsigned short ushort8 __attribute__((ext_vector_type(8)));
typedef unsigned short us4 __attribute__((ext_vector_type(4)));
typedef float f32x4 __attribute__((ext_vector_type(4)));
typedef int i32x4 __attribute__((ext_vector_type(4)));
typedef char char8v __attribute__((ext_vector_type(8)));

static __device__ __forceinline__ unsigned short f2bf(float f) {
  union { float f; unsigned int u; } v; v.f = f;
  unsigned int r = v.u + 0x7fffu + ((v.u >> 16) & 1u);
  return (unsigned short)(r >> 16);
}
static __device__ __forceinline__ float bf2f(unsigned short h) {
  union { unsigned int u; float f; } v; v.u = ((unsigned int)h) << 16;
  return v.f;
}

static __device__ __forceinline__ float fast_rcp(float x) {
  float r; asm("v_rcp_f32 %0, %1" : "=v"(r) : "v"(x)); return r;
}

// tanh-form GELU. |err vs erf| <= ~3e-3/elem, diluted by @W2.
static __device__ __forceinline__ float gelu_f(float v) {
  const float v2 = v * v;
  const float w = v * (0.7978845608f + 0.0356774081f * v2);
  const float a = fminf(w * 2.8853900818f, 126.0f);
  const float u = exp2f(a);
  return v * u * fast_rcp(u + 1.0f);
}

static __device__ __forceinline__ int q8i(float v, float inv) {
  int q = __float2int_rn(v * inv);
  q = q > 127 ? 127 : (q < -127 ? -127 : q);
  return q;
}
static __device__ __forceinline__ char q8(float v, float inv) {
  return (char)q8i(v, inv);
}

__device__ __forceinline__ void gload_lds16(const void* g, void* l) {
  __builtin_amdgcn_global_load_lds((const __attribute__((address_space(1))) void*)g,
                                   (__attribute__((address_space(3))) void*)l, 16, 0, 0);
}

#define H1S   (3.0f / 127.0f)
#define IH1S  (127.0f / 3.0f)

// kappa-permutation within each 128-col block
static __device__ __forceinline__ int kappa_to_c(int k128) {
  const int wcbit = k128 >> 6, lrow = (k128 & 63) >> 2, n = k128 & 3;
  return wcbit * 64 + n * 16 + lrow;
}
static __device__ __forceinline__ int c_to_kappa(int c128) {
  return (c128 >> 6) * 64 + (c128 & 15) * 4 + ((c128 & 63) >> 4);
}

// 4-chunk staging swizzle (64B rows)
static __device__ __forceinline__ int swz_kc(int q, int row) {
  return (q & 3) ^ ((row >> 1) & 3);
}
static __device__ __forceinline__ int swz_rd(int row, int lg) {
  return row * 4 + (lg ^ ((row >> 1) & 3));
}
// 8-chunk staging swizzle (128B rows, bf16 BK=64)
static __device__ __forceinline__ int swz8_kc(int q, int row) {
  return (q & 7) ^ ((row >> 1) & 7);
}
static __device__ __forceinline__ int swz8_rd(int row, int chunk) {
  return row * 8 + (chunk ^ ((row >> 1) & 7));
}

// ---------------- precompute stage A: kv + weight scales ----------------

__global__ __launch_bounds__(256) void pre_a(const float* __restrict__ aux,
                                             const float* __restrict__ Wkv,
                                             const float* __restrict__ bkv,
                                             const float* __restrict__ W1,
                                             const float* __restrict__ W2,
                                             float* __restrict__ kv,
                                             float* __restrict__ w1s,
                                             float* __restrict__ w2s) {
  __shared__ unsigned int red;
  const int bid = blockIdx.x;
  const int tid = threadIdx.x;
  if (bid < 256) {
    const int g = bid * 256 + tid;              // 65536 = 64 * 1024
    const int j = g >> 10, cc = g & 1023;
    float s = bkv[cc];
    for (int i = 0; i < C_; ++i) s += aux[j * C_ + i] * Wkv[i * (2 * C_) + cc];
    kv[g] = s;
    return;
  }
  const bool isW1 = bid < 256 + 1536;
  const int n = isW1 ? (bid - 256) : (bid - 256 - 1536);
  const int ROWS = isW1 ? 512 : 1536;
  const int NC   = isW1 ? 1536 : 512;
  const float* W = isW1 ? W1 : W2;
  if (tid == 0) red = 0;
  __syncthreads();
  float amax = 0.f;
  for (int k = tid; k < ROWS; k += 256)
    amax = fmaxf(amax, fabsf(W[(size_t)k * NC + n]));
#pragma unroll
  for (int off = 1; off < 64; off <<= 1)
    amax = fmaxf(amax, __shfl_xor(amax, off));
  if ((tid & 63) == 0) atomicMax(&red, __float_as_uint(amax));
  __syncthreads();
  if (tid == 0) (isW1 ? w1s : w2s)[n] = fmaxf(__uint_as_float(red), 1e-20f) / 127.0f;
}

// ---------------- precompute stage B: MT, cb, VoT(kappa) ----------------

__global__ __launch_bounds__(256) void pre_b(const float* __restrict__ Wq,
                                             const float* __restrict__ bq,
                                             const float* __restrict__ Wo,
                                             const float* __restrict__ kv,
                                             unsigned short* __restrict__ MT,
                                             float* __restrict__ cbias,
                                             unsigned short* __restrict__ VoT) {
  const int bid = blockIdx.x;
  const int tid = threadIdx.x;
  if (bid < 512) {
    const int col = bid;
    const int h = col >> 6, j = col & 63;
    const float* kvp = kv + j * 1024 + h * 64;
    for (int c = tid; c < C_; c += 256) {
      float s = 0.f;
      for (int d = 0; d < 64; ++d) s += Wq[(size_t)c * C_ + h * 64 + d] * kvp[d];
      MT[(size_t)col * C_ + c] = f2bf(0.125f * s);
    }
    if (tid == 0) {
      float s = 0.f;
      for (int d = 0; d < 64; ++d) s += bq[h * 64 + d] * kvp[d];
      cbias[col] = 0.125f * s;
    }
  } else {
    const int cp = bid - 512;
    for (int k = tid; k < 512; k += 256) {
      const int c = (k >> 7) * 128 + kappa_to_c(k & 127);   // true attention col
      const int h = c >> 6, j = c & 63;
      float s = 0.f;
      for (int d = 0; d < 64; ++d)
        s += kv[j * 1024 + 512 + h * 64 + d] * Wo[(size_t)(h * 64 + d) * C_ + cp];
      VoT[(size_t)cp * 512 + k] = f2bf(s);
    }
  }
}

// ---------------- precompute stage W: coalesced transpose-quantize of W1/W2 ----------------

__global__ __launch_bounds__(256) void pre_w(const float* __restrict__ W1,
                                             const float* __restrict__ W2,
                                             const float* __restrict__ w1s,
                                             const float* __restrict__ w2s,
                                             char* __restrict__ W1Q,
                                             char* __restrict__ W2Q) {
  __shared__ char tile[64 * 132];
  __shared__ float invs[64];
  const int bid = blockIdx.x, tid = threadIdx.x;
  const bool isW1 = bid < 96;
  int n0, k0, NC;
  if (isW1) { n0 = (bid >> 2) * 64; k0 = (bid & 3) * 128; NC = 1536; }
  else      { const int t = bid - 96; n0 = (t / 12) * 64; k0 = (t % 12) * 128; NC = 512; }
  const float* W = isW1 ? W1 : W2;
  if (tid < 64) invs[tid] = 1.0f / (isW1 ? w1s[n0 + tid] : w2s[n0 + tid]);
  __syncthreads();
  const int n = tid & 63;
  const float inv = invs[n];
#pragma unroll
  for (int s = 0; s < 32; ++s) {
    const int f = s * 256 + tid;
    const int r = f >> 6;                       // 0..127
    const int pr = isW1 ? r : c_to_kappa(r);    // kappa k-permutation for W2
    tile[n * 132 + pr] = q8(W[(size_t)(k0 + r) * NC + n0 + n], inv);
  }
  __syncthreads();
#pragma unroll
  for (int s = 0; s < 2; ++s) {
    const int idx = s * 256 + tid;              // 512 = 64n x 8kc
    const int nn = idx >> 3, kc = idx & 7;
    i32x4 pk;
#pragma unroll
    for (int j = 0; j < 4; ++j)
      pk[j] = *(const int*)&tile[nn * 132 + kc * 16 + j * 4];
    if (isW1) *(i32x4*)&W1Q[(size_t)(n0 + nn) * 512 + k0 + kc * 16] = pk;
    else      *(i32x4*)&W2Q[(size_t)(n0 + nn) * 1536 + k0 + kc * 16] = pk;
  }
}

// ---------------- x (B,C,T) -> xt bf16 (B*T, C), vectorized stores ----------------

__global__ __launch_bounds__(256) void xt_kernel(const float* __restrict__ x,
                                                 unsigned short* __restrict__ xt) {
  __shared__ float ld[64][65];
  const int tid = threadIdx.x;
  const int t0 = blockIdx.x * 64, c0 = blockIdx.y * 64, b = blockIdx.z;
  for (int idx = tid; idx < 4096; idx += 256) {
    const int r = idx >> 6, cc = idx & 63;
    ld[r][cc] = x[((size_t)(b * C_ + c0 + r)) * T_ + t0 + cc];
  }
  __syncthreads();
#pragma unroll
  for (int s = 0; s < 2; ++s) {
    const int idx = s * 256 + tid;      // 512 = 64 t-rows x 8 col-chunks
    const int tr = idx >> 3, cl8 = (idx & 7) * 8;
    ushort8 o;
#pragma unroll
    for (int qv = 0; qv < 8; ++qv) o[qv] = f2bf(ld[cl8 + qv][tr]);
    *(ushort8*)&xt[((size_t)(b * T_ + t0 + tr)) * C_ + c0 + cl8] = o;
  }
}

// ---------------- GEMM A (m97, BK=64, 8-chunk coalesced swizzled staging) ----------------
template<int N, int K, int NCOL, int EPI>
__global__ __launch_bounds__(256) void gemm_mfma(const unsigned short* __restrict__ A,
                                                 const unsigned short* __restrict__ Bt,
                                                 const float* __restrict__ bias,
                                                 unsigned short* __restrict__ outU,
                                                 const unsigned short* __restrict__ resU,
                                                 float* __restrict__ outF) {
  __shared__ __align__(16) unsigned short shm[EPI == 4 ? 128 * 132 : 128 * 128];
  unsigned short* lA = shm;              // 128 rows x 64 k (8 chunks/row)
  unsigned short* lB = shm + 128 * 64;
  unsigned short* bounce = shm;          // EPI4 only, after K-loop (lA/lB dead)
  const int q = gridDim.x >> 3;
  const int wgid = (blockIdx.x & 7) * q + (blockIdx.x >> 3);
  const int row0 = (wgid / NCOL) * 128;
  const int col0 = (wgid % NCOL) * 128;
  const int tid = threadIdx.x;
  const int w = tid >> 6, lane = tid & 63;
  const int wr = (w >> 1) * 64, wc = (w & 1) * 64;

  const f32x4 zero4 = {0.f, 0.f, 0.f, 0.f};
  f32x4 acc[4][4];
#pragma unroll
  for (int m = 0; m < 4; ++m)
#pragma unroll
    for (int n = 0; n < 4; ++n) acc[m][n] = zero4;

  const int lrow = lane & 15, lg = lane >> 4;

  // hoisted per-thread staging source pointers (one per s-slice)
  const unsigned short* aP[4];
  const unsigned short* bP[4];
#pragma unroll
  for (int s = 0; s < 4; ++s) {
    const int qq = s * 256 + tid;
    const int r = qq >> 3;
    const int kc = swz8_kc(qq, r);
    aP[s] = A + (size_t)(row0 + r) * K + kc * 8;
    bP[s] = Bt + (size_t)(col0 + r) * K + kc * 8;
  }

  for (int k0 = 0; k0 < K; k0 += 64) {
#pragma unroll
    for (int s = 0; s < 4; ++s) {
      const int qq = s * 256 + tid;
      gload_lds16(aP[s] + k0, (char*)lA + qq * 16);
      gload_lds16(bP[s] + k0, (char*)lB + qq * 16);
    }
    __syncthreads();
    short8 av[2][4], bv[2][4];
#pragma unroll
    for (int ks = 0; ks < 2; ++ks) {
      const int ch = ks * 4 + lg;
#pragma unroll
      for (int m = 0; m < 4; ++m) {
        const int ar = wr + m * 16 + lrow;
        av[ks][m] = *(const short8*)&lA[swz8_rd(ar, ch) * 8];
        const int br = wc + m * 16 + lrow;
        bv[ks][m] = *(const short8*)&lB[swz8_rd(br, ch) * 8];
      }
    }
#pragma unroll
    for (int ks = 0; ks < 2; ++ks)
#pragma unroll
      for (int m = 0; m < 4; ++m)
#pragma unroll
        for (int n = 0; n < 4; ++n)
          acc[m][n] = __builtin_amdgcn_mfma_f32_16x16x32_bf16(av[ks][m], bv[ks][n],
                                                              acc[m][n], 0, 0, 0);
    __syncthreads();
  }

  if (EPI == 1) {
    float cbv[4];
#pragma unroll
    for (int n = 0; n < 4; ++n) cbv[n] = bias[col0 + wc + n * 16 + lrow];
    const int kbase = col0 + wc + lrow * 4;
#pragma unroll
    for (int m = 0; m < 4; ++m) {
#pragma unroll
      for (int i = 0; i < 4; ++i) {
        float e0 = acc[m][0][i] + cbv[0];
        float e1 = acc[m][1][i] + cbv[1];
        float e2 = acc[m][2][i] + cbv[2];
        float e3 = acc[m][3][i] + cbv[3];
        float mx = fmaxf(fmaxf(e0, e1), fmaxf(e2, e3));
        mx = fmaxf(mx, __shfl_xor(mx, 1));
        mx = fmaxf(mx, __shfl_xor(mx, 2));
        mx = fmaxf(mx, __shfl_xor(mx, 4));
        mx = fmaxf(mx, __shfl_xor(mx, 8));
        e0 = __expf(e0 - mx); e1 = __expf(e1 - mx);
        e2 = __expf(e2 - mx); e3 = __expf(e3 - mx);
        float s = e0 + e1 + e2 + e3;
        s += __shfl_xor(s, 1);
        s += __shfl_xor(s, 2);
        s += __shfl_xor(s, 4);
        s += __shfl_xor(s, 8);
        const float inv = 1.0f / s;
        us4 pk;
        pk[0] = f2bf(e0 * inv); pk[1] = f2bf(e1 * inv);
        pk[2] = f2bf(e2 * inv); pk[3] = f2bf(e3 * inv);
        *(us4*)&outU[(size_t)(row0 + wr + m * 16 + lg * 4 + i) * N + kbase] = pk;
      }
    }
    return;
  }

  // EPI == 4 : residual epilogue with LDS transpose bounce
#pragma unroll
  for (int m = 0; m < 4; ++m) {
    const int r0 = row0 + wr + m * 16 + (lg << 2);
    const int tl = wr + m * 16 + (lg << 2);
#pragma unroll
    for (int n = 0; n < 4; ++n) {
      const int cl = wc + n * 16 + lrow;
      const int c = col0 + cl;
      const float bb = bias[c];
      us4 pk;
#pragma unroll
      for (int i = 0; i < 4; ++i)
        pk[i] = f2bf(bf2f(resU[(size_t)(r0 + i) * 512 + c]) + acc[m][n][i] + bb);
      *(us4*)&bounce[cl * 132 + tl] = pk;
    }
  }
  __syncthreads();
  const int bidx = row0 >> 12;
  const int t0 = row0 & 4095;
#pragma unroll
  for (int j = 0; j < 8; ++j) {
    const int cl = j * 16 + w * 4 + (lane >> 4);
    const int t = (lane & 15) * 8;
    const ushort8 v = *(const ushort8*)&bounce[cl * 132 + t];
    *(ushort8*)&outU[((size_t)(bidx * C_ + col0 + cl)) * T_ + t0 + t] = v;
  }
}

// ---------------- GEMM B: int8, 8 waves, 128x256 tile, BK=64, 3-buf, coalesced staging ------
template<int N, int K, int NCOL, int EPI>
__global__ __launch_bounds__(512, 4) void gemm8w(const char* __restrict__ A,
                                                 const char* __restrict__ Bt,
                                                 const float* __restrict__ rowS,
                                                 const float* __restrict__ colS,
                                                 const float* __restrict__ bias,
                                                 char* __restrict__ outQ,
                                                 const unsigned short* __restrict__ resU,
                                                 float* __restrict__ outF) {
  __shared__ __align__(16) char lds[73728];
  const int tid = threadIdx.x;
  const int w = tid >> 6, lane = tid & 63;
  const int wm = w >> 2, wn = w & 3;            // 2x4 wave grid
  const int lrow = lane & 15, lg = lane >> 4;
  const int q8g = gridDim.x >> 3;
  const int wgid = (blockIdx.x & 7) * q8g + (blockIdx.x >> 3);
  const int row0 = (wgid / NCOL) * 128;
  const int col0 = (wgid % NCOL) * 128 * 2;     // BN=256

  // hoisted per-thread staging source pointers
  const char* aP0;
  const char* bP0;
  const char* bP1;
  {
    const int rA = tid >> 2, kcA = swz_kc(tid, rA);
    aP0 = A + (size_t)(row0 + rA) * K + kcA * 16;
    bP0 = Bt + (size_t)(col0 + rA) * K + kcA * 16;
    const int q1 = 512 + tid;
    const int r1b = q1 >> 2, kc1 = swz_kc(q1, r1b);
    bP1 = Bt + (size_t)(col0 + r1b) * K + kc1 * 16;
  }
  auto stageA = [&](int kt, int b) {
    gload_lds16(aP0 + kt * 64, lds + b * 8192 + tid * 16);
  };
  auto stageB = [&](int kt, int b) {
    gload_lds16(bP0 + kt * 64, lds + 24576 + b * 16384 + tid * 16);
    gload_lds16(bP1 + kt * 64, lds + 24576 + b * 16384 + (512 + tid) * 16);
  };

  const i32x4 zero4 = {0, 0, 0, 0};
  i32x4 acc[4][4];
#pragma unroll
  for (int m = 0; m < 4; ++m)
#pragma unroll
    for (int n = 0; n < 4; ++n) acc[m][n] = zero4;

  const int KT = K / 64;     // G3: 8, G4: 24

  stageA(0, 0); stageB(0, 0);
  stageA(1, 1); stageB(1, 1);
  asm volatile("s_waitcnt vmcnt(3)" ::: "memory");
  __builtin_amdgcn_s_barrier();

  int cur = 0;
  for (int t = 0; t < KT; ++t) {
    if (t + 2 < KT) {
      const int nb = (cur + 2 >= 3) ? cur - 1 : cur + 2;
      stageA(t + 2, nb); stageB(t + 2, nb);
    }
    const char* ab = lds + cur * 8192;
    const char* bb = lds + 24576 + cur * 16384;
    i32x4 av[4], bv[4];
#pragma unroll
    for (int mf = 0; mf < 4; ++mf) {
      const int ar = wm * 64 + mf * 16 + lrow;
      av[mf] = *(const i32x4*)(ab + (size_t)swz_rd(ar, lg) * 16);
    }
#pragma unroll
    for (int nf = 0; nf < 4; ++nf) {
      const int br = wn * 64 + nf * 16 + lrow;
      bv[nf] = *(const i32x4*)(bb + (size_t)swz_rd(br, lg) * 16);
    }
    __builtin_amdgcn_s_setprio(1);
#pragma unroll
    for (int mf = 0; mf < 4; ++mf)
#pragma unroll
      for (int nf = 0; nf < 4; ++nf)
        acc[mf][nf] = __builtin_amdgcn_mfma_i32_16x16x64_i8(av[mf], bv[nf],
                                                            acc[mf][nf], 0, 0, 0);
    __builtin_amdgcn_s_setprio(0);
    if (t + 2 < KT) { asm volatile("s_waitcnt vmcnt(3)" ::: "memory"); }
    else            { asm volatile("s_waitcnt vmcnt(0)" ::: "memory"); }
    __builtin_amdgcn_s_barrier();
    cur = (cur == 2) ? 0 : cur + 1;
  }

  if (EPI == 3) {
    const int kbase = col0 + (wn >> 1) * 128 + (wn & 1) * 64 + lrow * 4;
#pragma unroll
    for (int mf = 0; mf < 4; ++mf) {
      const int r0 = row0 + wm * 64 + mf * 16 + lg * 4;
      float rs4[4];
#pragma unroll
      for (int i = 0; i < 4; ++i) rs4[i] = rowS[r0 + i];
      float dsv[4], bbv[4];
#pragma unroll
      for (int nf = 0; nf < 4; ++nf) {
        const int c = col0 + wn * 64 + nf * 16 + lrow;
        dsv[nf] = colS[c];
        bbv[nf] = bias[c];
      }
#pragma unroll
      for (int i = 0; i < 4; ++i) {
        unsigned int pk = 0;
#pragma unroll
        for (int nf = 0; nf < 4; ++nf) {
          const float v = fmaf((float)acc[mf][nf][i], rs4[i] * dsv[nf], bbv[nf]);
          const float g = gelu_f(v);
          const unsigned int b = (unsigned int)(unsigned char)(char)q8i(g, IH1S);
          pk |= b << (8 * nf);
        }
        *(unsigned int*)&outQ[(size_t)(r0 + i) * N + kbase] = pk;
      }
    }
    return;
  }

  // EPI == 5 : 2-pass LDS bounce (128c x 128t f32, stride 132) -> coalesced stores
  float* fb = (float*)lds;
  const int bidx = row0 >> 12;
  const int t0 = row0 & 4095;
#pragma unroll
  for (int p = 0; p < 2; ++p) {
    if ((wn >> 1) == p) {
#pragma unroll
      for (int mf = 0; mf < 4; ++mf) {
        const int tl = wm * 64 + mf * 16 + lg * 4;
#pragma unroll
        for (int nf = 0; nf < 4; ++nf) {
          const int cl = (wn & 1) * 64 + nf * 16 + lrow;
          const int c = col0 + p * 128 + cl;
          const float ds = H1S * colS[c];
          const float bb = bias[c];
          f32x4 v;
#pragma unroll
          for (int i = 0; i < 4; ++i) v[i] = fmaf((float)acc[mf][nf][i], ds, bb);
          *(f32x4*)&fb[cl * 132 + tl] = v;
        }
      }
    }
    __syncthreads();
#pragma unroll
    for (int j = 0; j < 8; ++j) {
      const int cl = j * 16 + w * 2 + (lane >> 5);
      const int t = (lane & 31) * 4;
      const f32x4 v = *(const f32x4*)&fb[cl * 132 + t];
      const size_t addr = ((size_t)(bidx * C_ + col0 + p * 128 + cl)) * T_ + t0 + t;
      const us4 rv = *(const us4*)&resU[addr];
      f32x4 o;
#pragma unroll
      for (int i = 0; i < 4; ++i) o[i] = v[i] + bf2f(rv[i]);
      *(f32x4*)&outF[addr] = o;
    }
    __syncthreads();
  }
}

// ---------------- fused conv1d(k=7,p=3) + AdaLayerNorm -> int8 yln + per-token scale --------

__global__ __launch_bounds__(256) void convq_kernel(
    const unsigned short* __restrict__ rs,
    const float* __restrict__ dww,
    const float* __restrict__ dwb,
    const int* __restrict__ ids,
    const float* __restrict__ sce,
    const float* __restrict__ she,
    char* __restrict__ ylnq,
    float* __restrict__ yscale) {
  __shared__ unsigned short rbuf[512 * 28];   // [c][16t window + pad]
  __shared__ float cbuf[8 * 520];
  const int tid = threadIdx.x;
  const int t0 = blockIdx.x * 8;
  const int b = blockIdx.y;
  const int w0 = t0 - 4;                      // window [w0, w0+16)
#pragma unroll
  for (int s = 0; s < 8; ++s) {
    const int f = s * 256 + tid;
    const int c = f >> 2, j = f & 3;
    const int t = w0 + j * 4;
    us4 v = {0, 0, 0, 0};
    if (t >= 0 && t + 3 < T_) {
      v = *(const us4*)&rs[((size_t)(b * C_ + c)) * T_ + t];
    } else {
#pragma unroll
      for (int e = 0; e < 4; ++e)
        if (t + e >= 0 && t + e < T_) v[e] = rs[((size_t)(b * C_ + c)) * T_ + t + e];
    }
    *(us4*)&rbuf[c * 28 + j * 4] = v;
  }
  __syncthreads();
#pragma unroll
  for (int cc = 0; cc < 2; ++cc) {
    const int c = cc * 256 + tid;
    float f[15];
#pragma unroll
    for (int i = 0; i < 15; ++i) f[i] = bf2f(rbuf[c * 28 + i]);
    float wk[7];
#pragma unroll
    for (int k = 0; k < 7; ++k) wk[k] = dww[c * 7 + k];
    const float bb = dwb[c];
#pragma unroll
    for (int tt = 0; tt < 8; ++tt) {
      float s = bb;
#pragma unroll
      for (int k = 0; k < 7; ++k) s += f[tt + 1 + k] * wk[k];
      cbuf[tt * 520 + c] = s;
    }
  }
  __syncthreads();
  const int lane = tid & 63, w = tid >> 6;
  const int id = ids[b];
#pragma unroll
  for (int tt = 0; tt < 2; ++tt) {
    const int t = w * 2 + tt;
    const f32x4 v0 = *(const f32x4*)&cbuf[t * 520 + lane * 8];
    const f32x4 v1 = *(const f32x4*)&cbuf[t * 520 + lane * 8 + 4];
    float s = 0.f, sq = 0.f;
#pragma unroll
    for (int i = 0; i < 4; ++i) { s += v0[i]; sq += v0[i] * v0[i]; }
#pragma unroll
    for (int i = 0; i < 4; ++i) { s += v1[i]; sq += v1[i] * v1[i]; }
#pragma unroll
    for (int off = 1; off < 64; off <<= 1) {
      s += __shfl_xor(s, off);
      sq += __shfl_xor(sq, off);
    }
    const float mean = s * (1.0f / 512.0f);
    const float var = sq * (1.0f / 512.0f) - mean * mean;
    const float rstd = rsqrtf(var + 1e-6f);
    const f32x4 sc0 = *(const f32x4*)&sce[id * C_ + lane * 8];
    const f32x4 sc1 = *(const f32x4*)&sce[id * C_ + lane * 8 + 4];
    const f32x4 sh0 = *(const f32x4*)&she[id * C_ + lane * 8];
    const f32x4 sh1 = *(const f32x4*)&she[id * C_ + lane * 8 + 4];
    float y[8];
    float amax = 0.f;
#pragma unroll
    for (int i = 0; i < 4; ++i) {
      y[i]     = (v0[i] - mean) * rstd * sc0[i] + sh0[i];
      y[4 + i] = (v1[i] - mean) * rstd * sc1[i] + sh1[i];
    }
#pragma unroll
    for (int i = 0; i < 8; ++i) amax = fmaxf(amax, fabsf(y[i]));
#pragma unroll
    for (int off = 1; off < 64; off <<= 1) amax = fmaxf(amax, __shfl_xor(amax, off));
    amax = fmaxf(amax, 1e-20f);
    const float inv = 127.0f / amax;
    const int tg = b * T_ + t0 + t;
    char8v o;
#pragma unroll
    for (int i = 0; i < 8; ++i) o[i] = q8(y[i], inv);
    *(char8v*)&ylnq[(size_t)tg * C_ + lane * 8] = o;
    if (lane == 0) yscale[tg] = amax * (1.0f / 127.0f);
  }
}

// ---------------- launch ----------------

extern "C" void kernel_launch(void* const* d_in, const int* in_sizes, int n_in,
                              void* d_out, int out_size, void* d_ws, size_t ws_size,
                              hipStream_t stream) {
  const float* x   = (const float*)d_in[0];
  const int*   ids = (const int*)d_in[1];
  const float* Wq  = (const float*)d_in[2];
  const float* bq  = (const float*)d_in[3];
  const float* Wkv = (const float*)d_in[4];
  const float* bkv = (const float*)d_in[5];
  const float* Wo  = (const float*)d_in[6];
  const float* bo  = (const float*)d_in[7];
  const float* dww = (const float*)d_in[8];
  const float* dwb = (const float*)d_in[9];
  const float* sce = (const float*)d_in[10];
  const float* she = (const float*)d_in[11];
  const float* W1  = (const float*)d_in[12];
  const float* b1  = (const float*)d_in[13];
  const float* W2  = (const float*)d_in[14];
  const float* b2  = (const float*)d_in[15];
  const float* aux = (const float*)d_in[16];
  float* out = (float*)d_out;

  char* ws = (char*)d_ws;
  unsigned short* xt   = (unsigned short*)(ws + 0);              // 64 MB
  unsigned short* P    = (unsigned short*)(ws + (64u  << 20));   // 64 MB
  char*           ylnq = (char*)(ws + (64u << 20));              // 32 MB (overlays P; P dead)
  float*          ysc  = (float*)(ws + (100u << 20));            // 256 KB
  unsigned short* rs   = (unsigned short*)(ws + (128u << 20));   // 64 MB (bf16)
  char*           H1Q  = (char*)(ws + (192u << 20));             // 96 MB (i8)
  char* sm = ws + (384u << 20);
  float*          kv   = (float*)(sm);                           // 256 KB
  float*          cb   = (float*)(sm + 262144);                  // 2 KB
  unsigned short* MT   = (unsigned short*)(sm + 264192);         // 512 KB
  unsigned short* VoT  = (unsigned short*)(sm + 788480);         // 512 KB
  char*           W1Q  = (char*)(sm + 1312768);                  // 768 KB
  char*           W2Q  = (char*)(sm + 2099200);                  // 768 KB
  float*          w1s  = (float*)(sm + 2885632);                 // 6 KB
  float*          w2s  = (float*)(sm + 2891776);                 // 2 KB

  pre_a<<<dim3(2304), dim3(256), 0, stream>>>(aux, Wkv, bkv, W1, W2, kv, w1s, w2s);
  pre_b<<<dim3(1024), dim3(256), 0, stream>>>(Wq, bq, Wo, kv, MT, cb, VoT);
  pre_w<<<dim3(192),  dim3(256), 0, stream>>>(W1, W2, w1s, w2s, W1Q, W2Q);
  xt_kernel<<<dim3(64, 8, 16), dim3(256), 0, stream>>>(x, xt);

  // attention as two BK=64 m97-structure GEMMs with packed/bounced epilogues
  gemm_mfma<512, 512, 4, 1><<<dim3(2048), dim3(256), 0, stream>>>(
      xt, MT, cb, P, nullptr, nullptr);
  gemm_mfma<512, 512, 4, 4><<<dim3(2048), dim3(256), 0, stream>>>(
      P, VoT, bo, rs, xt, nullptr);
  convq_kernel<<<dim3(512, 16), dim3(256), 0, stream>>>(rs, dww, dwb, ids, sce, she,
                                                        ylnq, ysc);
  // MLP as two int8 8-wave GEMMs, coalesced staging + swizzled LDS chunks
  gemm8w<1536, 512, 6, 3><<<dim3(3072), dim3(512), 0, stream>>>(
      ylnq, W1Q, ysc, w1s, b1, H1Q, nullptr, nullptr);
  gemm8w<512, 1536, 2, 5><<<dim3(1024), dim3(512), 0, stream>>>(
      H1Q, W2Q, nullptr, w2s, b2, nullptr, rs, out);
}